// Round 1
// baseline (508.359 us; speedup 1.0000x reference)
//
#include <hip/hip_runtime.h>

// LinearAttention: B=4, S=4096, D=1024, H=16, DK=64
// out = ((phi(xq Wq^T) @ (phi(xk Wk^T)^T @ (xv Wv^T)) / (phi(q).Ksum + 1e-6)) Wo^T + bo
// All GEMMs in bf16 MFMA (threshold = 2% of max|ref| -> bf16 is safe).

typedef unsigned short ushort_t;
typedef __bf16 bf16x8 __attribute__((ext_vector_type(8)));
typedef float f32x4 __attribute__((ext_vector_type(4)));
typedef void gvoid_t __attribute__((address_space(1)));
typedef void svoid_t __attribute__((address_space(3)));

#define BB 4
#define SS 4096
#define DD 1024
#define HH 16
#define DKk 64
#define MM (BB * SS) /* 16384 */

__device__ __forceinline__ ushort_t f2bf(float f) {
  unsigned int u = __float_as_uint(f);
  u += 0x7fffu + ((u >> 16) & 1u); // RNE
  return (ushort_t)(u >> 16);
}
__device__ __forceinline__ float b2f(ushort_t h) {
  return __uint_as_float(((unsigned int)h) << 16);
}
__device__ __forceinline__ void gld_lds16(const ushort_t* g, ushort_t* l) {
  // async global->LDS, 16B per lane; LDS dest = wave-uniform base + lane*16
  __builtin_amdgcn_global_load_lds((gvoid_t*)g, (svoid_t*)l, 16, 0, 0);
}
__device__ __forceinline__ bf16x8 ldfrag(const ushort_t* p) {
  return *(const bf16x8*)p; // 16B aligned at all call sites
}

// ---------------- cast kernels (fp32 -> bf16) ----------------
__global__ __launch_bounds__(256) void cast3_kernel(
    const float* __restrict__ q, const float* __restrict__ k, const float* __restrict__ v,
    ushort_t* __restrict__ qd, ushort_t* __restrict__ kd, ushort_t* __restrict__ vd) {
  const int z = blockIdx.y;
  const float* s = (z == 0) ? q : (z == 1) ? k : v;
  ushort_t* d = (z == 0) ? qd : (z == 1) ? kd : vd;
  size_t i = ((size_t)blockIdx.x * 256 + threadIdx.x) * 4;
  float4 f = *(const float4*)(s + i);
  ushort4 o;
  o.x = f2bf(f.x); o.y = f2bf(f.y); o.z = f2bf(f.z); o.w = f2bf(f.w);
  *(ushort4*)(d + i) = o;
}

__global__ __launch_bounds__(256) void cast4_kernel(
    const float* __restrict__ a, const float* __restrict__ b,
    const float* __restrict__ c, const float* __restrict__ e,
    ushort_t* __restrict__ ad, ushort_t* __restrict__ bd,
    ushort_t* __restrict__ cd, ushort_t* __restrict__ ed) {
  const int z = blockIdx.y;
  const float* s = (z == 0) ? a : (z == 1) ? b : (z == 2) ? c : e;
  ushort_t* d = (z == 0) ? ad : (z == 1) ? bd : (z == 2) ? cd : ed;
  size_t i = ((size_t)blockIdx.x * 256 + threadIdx.x) * 4;
  float4 f = *(const float4*)(s + i);
  ushort4 o;
  o.x = f2bf(f.x); o.y = f2bf(f.y); o.z = f2bf(f.z); o.w = f2bf(f.w);
  *(ushort4*)(d + i) = o;
}

// ---------------- projection GEMM: Y = act(A[M,K] * W[N,K]^T) -> bf16 ------
// m97 structure: 128x128 tile, BK=32, 4 waves, 4x4 16x16x32 frags per wave.
__global__ __launch_bounds__(256) void proj_kernel(
    const ushort_t* __restrict__ qa, const ushort_t* __restrict__ ka, const ushort_t* __restrict__ va,
    const ushort_t* __restrict__ wq, const ushort_t* __restrict__ wk, const ushort_t* __restrict__ wv,
    ushort_t* __restrict__ Qp, ushort_t* __restrict__ Kp, ushort_t* __restrict__ Vp) {
  const int z = blockIdx.z;
  const ushort_t* A = (z == 0) ? qa : (z == 1) ? ka : va;
  const ushort_t* Bw = (z == 0) ? wq : (z == 1) ? wk : wv;
  ushort_t* Y = (z == 0) ? Qp : (z == 1) ? Kp : Vp;
  const bool act = (z < 2); // phi = elu+1 on Q,K only

  __shared__ __align__(16) ushort_t Ash[128 * 32];
  __shared__ __align__(16) ushort_t Bsh[128 * 32];
  const int t = threadIdx.x;
  const int m0 = blockIdx.y * 128, n0 = blockIdx.x * 128;
  const int w = t >> 6, lane = t & 63, q4 = lane >> 4, l16 = lane & 15;
  const int wm = (w >> 1) * 64, wn = (w & 1) * 64;

  f32x4 acc[4][4];
  const f32x4 zero = {0.f, 0.f, 0.f, 0.f};
#pragma unroll
  for (int i = 0; i < 4; i++)
#pragma unroll
    for (int j = 0; j < 4; j++) acc[i][j] = zero;

  for (int k0 = 0; k0 < 1024; k0 += 32) {
#pragma unroll
    for (int it = 0; it < 2; it++) {
      int lin = it * 256 + t;
      int row = lin >> 2, ch = (lin & 3) * 8;
      gld_lds16(A + (size_t)(m0 + row) * 1024 + k0 + ch, Ash + lin * 8);
      gld_lds16(Bw + (size_t)(n0 + row) * 1024 + k0 + ch, Bsh + lin * 8);
    }
    __syncthreads(); // drains vmcnt for global_load_lds
    bf16x8 af[4], bfm[4];
#pragma unroll
    for (int mi = 0; mi < 4; mi++) af[mi] = ldfrag(&Ash[(wm + mi * 16 + l16) * 32 + q4 * 8]);
#pragma unroll
    for (int ni = 0; ni < 4; ni++) bfm[ni] = ldfrag(&Bsh[(wn + ni * 16 + l16) * 32 + q4 * 8]);
#pragma unroll
    for (int mi = 0; mi < 4; mi++)
#pragma unroll
      for (int ni = 0; ni < 4; ni++)
        acc[mi][ni] = __builtin_amdgcn_mfma_f32_16x16x32_bf16(af[mi], bfm[ni], acc[mi][ni], 0, 0, 0);
    __syncthreads();
  }
#pragma unroll
  for (int mi = 0; mi < 4; mi++)
#pragma unroll
    for (int ni = 0; ni < 4; ni++) {
      int col = n0 + wn + ni * 16 + l16;
#pragma unroll
      for (int r = 0; r < 4; r++) {
        int row = m0 + wm + mi * 16 + q4 * 4 + r;
        float vv = acc[mi][ni][r];
        if (act) vv = (vv > 0.f) ? (vv + 1.f) : __expf(vv); // elu(x)+1
        Y[(size_t)row * 1024 + col] = f2bf(vv);
      }
    }
}

// ---------------- output GEMM: out = A * Wo^T + bo -> fp32 ----------------
__global__ __launch_bounds__(256) void out_kernel(
    const ushort_t* __restrict__ A, const ushort_t* __restrict__ Bw,
    float* __restrict__ Of, const float* __restrict__ bias) {
  __shared__ __align__(16) ushort_t Ash[128 * 32];
  __shared__ __align__(16) ushort_t Bsh[128 * 32];
  const int t = threadIdx.x;
  const int m0 = blockIdx.y * 128, n0 = blockIdx.x * 128;
  const int w = t >> 6, lane = t & 63, q4 = lane >> 4, l16 = lane & 15;
  const int wm = (w >> 1) * 64, wn = (w & 1) * 64;

  f32x4 acc[4][4];
  const f32x4 zero = {0.f, 0.f, 0.f, 0.f};
#pragma unroll
  for (int i = 0; i < 4; i++)
#pragma unroll
    for (int j = 0; j < 4; j++) acc[i][j] = zero;

  for (int k0 = 0; k0 < 1024; k0 += 32) {
#pragma unroll
    for (int it = 0; it < 2; it++) {
      int lin = it * 256 + t;
      int row = lin >> 2, ch = (lin & 3) * 8;
      gld_lds16(A + (size_t)(m0 + row) * 1024 + k0 + ch, Ash + lin * 8);
      gld_lds16(Bw + (size_t)(n0 + row) * 1024 + k0 + ch, Bsh + lin * 8);
    }
    __syncthreads();
    bf16x8 af[4], bfm[4];
#pragma unroll
    for (int mi = 0; mi < 4; mi++) af[mi] = ldfrag(&Ash[(wm + mi * 16 + l16) * 32 + q4 * 8]);
#pragma unroll
    for (int ni = 0; ni < 4; ni++) bfm[ni] = ldfrag(&Bsh[(wn + ni * 16 + l16) * 32 + q4 * 8]);
#pragma unroll
    for (int mi = 0; mi < 4; mi++)
#pragma unroll
      for (int ni = 0; ni < 4; ni++)
        acc[mi][ni] = __builtin_amdgcn_mfma_f32_16x16x32_bf16(af[mi], bfm[ni], acc[mi][ni], 0, 0, 0);
    __syncthreads();
  }
#pragma unroll
  for (int mi = 0; mi < 4; mi++)
#pragma unroll
    for (int ni = 0; ni < 4; ni++) {
      int col = n0 + wn + ni * 16 + l16;
      float bv = bias[col];
#pragma unroll
      for (int r = 0; r < 4; r++) {
        int row = m0 + wm + mi * 16 + q4 * 4 + r;
        Of[(size_t)row * 1024 + col] = acc[mi][ni][r] + bv;
      }
    }
}

// ---------------- KV kernel: KVt[bh][e][d] = sum_s V[s,e]*K[s,d]; Ksum[bh][d]
// grid (4 s-chunks, 64 bh). MFMA with LDS-transposed reads (pad stride 66).
__global__ __launch_bounds__(256) void kv_kernel(
    const ushort_t* __restrict__ Kp, const ushort_t* __restrict__ Vp,
    float* __restrict__ KVt, float* __restrict__ Ksum) {
  const int bh = blockIdx.y, b = bh >> 4, h = bh & 15;
  const int schunk = blockIdx.x * 1024;
  const int t = threadIdx.x, w = t >> 6, lane = t & 63, q4 = lane >> 4, l16 = lane & 15;
  __shared__ ushort_t Ksh[64 * 66]; // row stride 66 ushorts = 33 dwords -> conflict-free transposed u16 reads
  __shared__ ushort_t Vsh[64 * 66];
  __shared__ float red[4][64];

  f32x4 acc[4];
  const f32x4 zero = {0.f, 0.f, 0.f, 0.f};
#pragma unroll
  for (int i = 0; i < 4; i++) acc[i] = zero;
  float ksum = 0.f;

  const int mat = t >> 7, tl = t & 127;
  const ushort_t* src = mat ? Vp : Kp;
  ushort_t* dsh = mat ? Vsh : Ksh;

  for (int tile = 0; tile < 16; tile++) {
    const int s0 = schunk + tile * 64;
    // stage 64x64 bf16 of K and V (threads 0..127 -> K, 128..255 -> V)
#pragma unroll
    for (int i = 0; i < 4; i++) {
      int idx = i * 1024 + tl * 8;
      int r = idx >> 6, c = idx & 63;
      const ushort_t* g = src + (size_t)(b * 4096 + s0 + r) * 1024 + h * 64 + c;
      uint4 u = *(const uint4*)g;
      unsigned int* p = (unsigned int*)&dsh[r * 66 + c];
      p[0] = u.x; p[1] = u.y; p[2] = u.z; p[3] = u.w;
    }
    __syncthreads();
    // wave w owns d-group [16w,16w+16); mi loops e-groups
#pragma unroll
    for (int ks = 0; ks < 2; ks++) {
      ushort_t tb[8];
#pragma unroll
      for (int j = 0; j < 8; j++) tb[j] = Ksh[(ks * 32 + q4 * 8 + j) * 66 + w * 16 + l16];
      bf16x8 bfr; __builtin_memcpy(&bfr, tb, 16);
#pragma unroll
      for (int mi = 0; mi < 4; mi++) {
        ushort_t ta[8];
#pragma unroll
        for (int j = 0; j < 8; j++) ta[j] = Vsh[(ks * 32 + q4 * 8 + j) * 66 + mi * 16 + l16];
        bf16x8 afr; __builtin_memcpy(&afr, ta, 16);
        acc[mi] = __builtin_amdgcn_mfma_f32_16x16x32_bf16(afr, bfr, acc[mi], 0, 0, 0);
      }
    }
    // Ksum partial: thread t sums rows [(t>>6)*16, +16) at col d = t&63
    {
      int d = t & 63;
#pragma unroll
      for (int r = 0; r < 16; r++) ksum += b2f(Ksh[((t >> 6) * 16 + r) * 66 + d]);
    }
    __syncthreads();
  }
  // C layout: row(m=e) = mi*16 + q4*4 + r ; col(n=d) = w*16 + l16
#pragma unroll
  for (int mi = 0; mi < 4; mi++)
#pragma unroll
    for (int r = 0; r < 4; r++) {
      int e = mi * 16 + q4 * 4 + r, d = w * 16 + l16;
      atomicAdd(&KVt[(size_t)bh * 4096 + e * 64 + d], acc[mi][r]);
    }
  red[t >> 6][t & 63] = ksum;
  __syncthreads();
  if (t < 64) atomicAdd(&Ksum[bh * 64 + t], red[0][t] + red[1][t] + red[2][t] + red[3][t]);
}

// ---------------- num kernel: Oc[s, h*64+e] = (Q_h KVt_h^T)/(Q_h.Ksum_h+1e-6)
// grid (16 s-tiles of 256, 64 bh)
__global__ __launch_bounds__(256) void num_kernel(
    const ushort_t* __restrict__ Qp, const float* __restrict__ KVt,
    const float* __restrict__ Ksum, ushort_t* __restrict__ Oc) {
  const int bh = blockIdx.y, b = bh >> 4, h = bh & 15;
  const int sblk = blockIdx.x * 256;
  const int t = threadIdx.x, w = t >> 6, lane = t & 63, q4 = lane >> 4, l16 = lane & 15;
  __shared__ __align__(16) ushort_t KVsh[64 * 72]; // stride 72 -> conflict-free b128 reads
  __shared__ float Ks_sh[64];
  __shared__ float rden[256];

#pragma unroll
  for (int i = 0; i < 16; i++) {
    int idx = i * 256 + t;
    int e = idx >> 6, d = idx & 63;
    KVsh[e * 72 + d] = f2bf(KVt[(size_t)bh * 4096 + idx]);
  }
  if (t < 64) Ks_sh[t] = Ksum[bh * 64 + t];
  __syncthreads();

  { // denominator for row sblk+t
    const ushort_t* qrow = Qp + (size_t)(b * 4096 + sblk + t) * 1024 + h * 64;
    float den = 1e-6f;
#pragma unroll
    for (int d = 0; d < 64; d++) den += b2f(qrow[d]) * Ks_sh[d];
    rden[t] = 1.f / den; // phi>0 -> den>0
  }
  __syncthreads();

  f32x4 acc[4][4];
  const f32x4 zero = {0.f, 0.f, 0.f, 0.f};
#pragma unroll
  for (int i = 0; i < 4; i++)
#pragma unroll
    for (int j = 0; j < 4; j++) acc[i][j] = zero;

#pragma unroll
  for (int ks = 0; ks < 2; ks++) {
    bf16x8 af[4], bfr[4];
#pragma unroll
    for (int mi = 0; mi < 4; mi++)
      af[mi] = ldfrag(Qp + (size_t)(b * 4096 + sblk + w * 64 + mi * 16 + l16) * 1024 + h * 64 + ks * 32 + q4 * 8);
#pragma unroll
    for (int ni = 0; ni < 4; ni++)
      bfr[ni] = ldfrag(&KVsh[(ni * 16 + l16) * 72 + ks * 32 + q4 * 8]);
#pragma unroll
    for (int mi = 0; mi < 4; mi++)
#pragma unroll
      for (int ni = 0; ni < 4; ni++)
        acc[mi][ni] = __builtin_amdgcn_mfma_f32_16x16x32_bf16(af[mi], bfr[ni], acc[mi][ni], 0, 0, 0);
  }
#pragma unroll
  for (int mi = 0; mi < 4; mi++)
#pragma unroll
    for (int ni = 0; ni < 4; ni++) {
      int e = ni * 16 + l16;
#pragma unroll
      for (int r = 0; r < 4; r++) {
        int srow = w * 64 + mi * 16 + q4 * 4 + r;
        float vv = acc[mi][ni][r] * rden[srow];
        Oc[(size_t)(b * 4096 + sblk + srow) * 1024 + h * 64 + e] = f2bf(vv);
      }
    }
}

extern "C" void kernel_launch(void* const* d_in, const int* in_sizes, int n_in,
                              void* d_out, int out_size, void* d_ws, size_t ws_size,
                              hipStream_t stream) {
  const float* q  = (const float*)d_in[0];
  const float* k  = (const float*)d_in[1];
  const float* v  = (const float*)d_in[2];
  const float* Wq = (const float*)d_in[3];
  const float* Wk = (const float*)d_in[4];
  const float* Wv = (const float*)d_in[5];
  const float* Wo = (const float*)d_in[6];
  const float* bo = (const float*)d_in[7];

  char* ws = (char*)d_ws;
  const size_t SZ_IN = (size_t)MM * DD * 2; // 33,554,432 B per bf16 [16384,1024]
  ushort_t* qbf = (ushort_t*)(ws);
  ushort_t* kbf = (ushort_t*)(ws + SZ_IN);
  ushort_t* vbf = (ushort_t*)(ws + 2 * SZ_IN);
  ushort_t* wqb = (ushort_t*)(ws + 3 * SZ_IN);
  ushort_t* wkb = wqb + (size_t)1024 * 1024;
  ushort_t* wvb = wkb + (size_t)1024 * 1024;
  ushort_t* wob = wvb + (size_t)1024 * 1024;
  ushort_t* Qp  = (ushort_t*)(ws + 3 * SZ_IN + 4 * (size_t)2097152);
  ushort_t* Kp  = Qp + (size_t)MM * DD;
  ushort_t* Vp  = Kp + (size_t)MM * DD;
  float* KVt    = (float*)((char*)(Vp + (size_t)MM * DD));
  float* KsumP  = KVt + (size_t)64 * 4096;
  ushort_t* Oc  = qbf; // reuse: qbf dead after proj dispatch
  float* outp   = (float*)d_out;

  hipMemsetAsync(KVt, 0, ((size_t)64 * 4096 + 64 * 64) * sizeof(float), stream);
  cast3_kernel<<<dim3(16384, 3), 256, 0, stream>>>(q, k, v, qbf, kbf, vbf);
  cast4_kernel<<<dim3(1024, 4), 256, 0, stream>>>(Wq, Wk, Wv, Wo, wqb, wkb, wvb, wob);
  proj_kernel<<<dim3(8, 128, 3), 256, 0, stream>>>(qbf, kbf, vbf, wqb, wkb, wvb, Qp, Kp, Vp);
  kv_kernel<<<dim3(4, 64), 256, 0, stream>>>(Kp, Vp, KVt, KsumP);
  num_kernel<<<dim3(16, 64), 256, 0, stream>>>(Qp, KVt, KsumP, Oc);
  out_kernel<<<dim3(8, 128), 256, 0, stream>>>(Oc, wob, outp, bo);
}

// Round 2
// 490.267 us; speedup vs baseline: 1.0369x; 1.0369x over previous
//
#include <hip/hip_runtime.h>

// LinearAttention: B=4, S=4096, D=1024, H=16, DK=64
// out = ((phi(xq Wq^T) @ (phi(xk Wk^T)^T @ (xv Wv^T)) / (phi(q).Ksum + 1e-6)) Wo^T + bo
// All GEMMs in bf16 MFMA (threshold = 2% of max|ref| -> bf16 is safe).
// R2: XCD-aware swizzle in proj/out. gridDim.x=8 -> XCD = blockIdx.x under
// round-robin; remap (x,y) so each XCD's concurrent A+B footprint fits its
// 4 MB L2 (was 24 MB A -> thrash -> 8.2 TB/s staging vs m97's 13.4).

typedef unsigned short ushort_t;
typedef __bf16 bf16x8 __attribute__((ext_vector_type(8)));
typedef float f32x4 __attribute__((ext_vector_type(4)));
typedef void gvoid_t __attribute__((address_space(1)));
typedef void svoid_t __attribute__((address_space(3)));

#define BB 4
#define SS 4096
#define DD 1024
#define HH 16
#define DKk 64
#define MM (BB * SS) /* 16384 */

__device__ __forceinline__ ushort_t f2bf(float f) {
  unsigned int u = __float_as_uint(f);
  u += 0x7fffu + ((u >> 16) & 1u); // RNE
  return (ushort_t)(u >> 16);
}
__device__ __forceinline__ float b2f(ushort_t h) {
  return __uint_as_float(((unsigned int)h) << 16);
}
__device__ __forceinline__ void gld_lds16(const ushort_t* g, ushort_t* l) {
  // async global->LDS, 16B per lane; LDS dest = wave-uniform base + lane*16
  __builtin_amdgcn_global_load_lds((gvoid_t*)g, (svoid_t*)l, 16, 0, 0);
}
__device__ __forceinline__ bf16x8 ldfrag(const ushort_t* p) {
  return *(const bf16x8*)p; // 16B aligned at all call sites
}

// ---------------- cast kernels (fp32 -> bf16) ----------------
__global__ __launch_bounds__(256) void cast3_kernel(
    const float* __restrict__ q, const float* __restrict__ k, const float* __restrict__ v,
    ushort_t* __restrict__ qd, ushort_t* __restrict__ kd, ushort_t* __restrict__ vd) {
  const int z = blockIdx.y;
  const float* s = (z == 0) ? q : (z == 1) ? k : v;
  ushort_t* d = (z == 0) ? qd : (z == 1) ? kd : vd;
  size_t i = ((size_t)blockIdx.x * 256 + threadIdx.x) * 4;
  float4 f = *(const float4*)(s + i);
  ushort4 o;
  o.x = f2bf(f.x); o.y = f2bf(f.y); o.z = f2bf(f.z); o.w = f2bf(f.w);
  *(ushort4*)(d + i) = o;
}

__global__ __launch_bounds__(256) void cast4_kernel(
    const float* __restrict__ a, const float* __restrict__ b,
    const float* __restrict__ c, const float* __restrict__ e,
    ushort_t* __restrict__ ad, ushort_t* __restrict__ bd,
    ushort_t* __restrict__ cd, ushort_t* __restrict__ ed) {
  const int z = blockIdx.y;
  const float* s = (z == 0) ? a : (z == 1) ? b : (z == 2) ? c : e;
  ushort_t* d = (z == 0) ? ad : (z == 1) ? bd : (z == 2) ? cd : ed;
  size_t i = ((size_t)blockIdx.x * 256 + threadIdx.x) * 4;
  float4 f = *(const float4*)(s + i);
  ushort4 o;
  o.x = f2bf(f.x); o.y = f2bf(f.y); o.z = f2bf(f.z); o.w = f2bf(f.w);
  *(ushort4*)(d + i) = o;
}

// ---------------- projection GEMM: Y = act(A[M,K] * W[N,K]^T) -> bf16 ------
// m97 structure: 128x128 tile, BK=32, 4 waves, 4x4 16x16x32 frags per wave.
__global__ __launch_bounds__(256) void proj_kernel(
    const ushort_t* __restrict__ qa, const ushort_t* __restrict__ ka, const ushort_t* __restrict__ va,
    const ushort_t* __restrict__ wq, const ushort_t* __restrict__ wk, const ushort_t* __restrict__ wv,
    ushort_t* __restrict__ Qp, ushort_t* __restrict__ Kp, ushort_t* __restrict__ Vp) {
  const int z = blockIdx.z;
  const ushort_t* A = (z == 0) ? qa : (z == 1) ? ka : va;
  const ushort_t* Bw = (z == 0) ? wq : (z == 1) ? wk : wv;
  ushort_t* Y = (z == 0) ? Qp : (z == 1) ? Kp : Vp;
  const bool act = (z < 2); // phi = elu+1 on Q,K only

  __shared__ __align__(16) ushort_t Ash[128 * 32];
  __shared__ __align__(16) ushort_t Bsh[128 * 32];
  const int t = threadIdx.x;
  // XCD swizzle: r = blockIdx.x is the XCD (gridDim.x=8, round-robin).
  // Per-XCD concurrent footprint: 8 A-tiles + 8 B-tiles = 4 MB -> fits L2.
  const int r_ = blockIdx.x, u_ = blockIdx.y;
  const int yb = r_ + 8 * (u_ & 7) + 64 * (u_ >> 6);
  const int xb = (u_ >> 3) & 7;
  const int m0 = yb * 128, n0 = xb * 128;
  const int w = t >> 6, lane = t & 63, q4 = lane >> 4, l16 = lane & 15;
  const int wm = (w >> 1) * 64, wn = (w & 1) * 64;

  f32x4 acc[4][4];
  const f32x4 zero = {0.f, 0.f, 0.f, 0.f};
#pragma unroll
  for (int i = 0; i < 4; i++)
#pragma unroll
    for (int j = 0; j < 4; j++) acc[i][j] = zero;

  for (int k0 = 0; k0 < 1024; k0 += 32) {
#pragma unroll
    for (int it = 0; it < 2; it++) {
      int lin = it * 256 + t;
      int row = lin >> 2, ch = (lin & 3) * 8;
      gld_lds16(A + (size_t)(m0 + row) * 1024 + k0 + ch, Ash + lin * 8);
      gld_lds16(Bw + (size_t)(n0 + row) * 1024 + k0 + ch, Bsh + lin * 8);
    }
    __syncthreads(); // drains vmcnt for global_load_lds
    bf16x8 af[4], bfm[4];
#pragma unroll
    for (int mi = 0; mi < 4; mi++) af[mi] = ldfrag(&Ash[(wm + mi * 16 + l16) * 32 + q4 * 8]);
#pragma unroll
    for (int ni = 0; ni < 4; ni++) bfm[ni] = ldfrag(&Bsh[(wn + ni * 16 + l16) * 32 + q4 * 8]);
#pragma unroll
    for (int mi = 0; mi < 4; mi++)
#pragma unroll
      for (int ni = 0; ni < 4; ni++)
        acc[mi][ni] = __builtin_amdgcn_mfma_f32_16x16x32_bf16(af[mi], bfm[ni], acc[mi][ni], 0, 0, 0);
    __syncthreads();
  }
#pragma unroll
  for (int mi = 0; mi < 4; mi++)
#pragma unroll
    for (int ni = 0; ni < 4; ni++) {
      int col = n0 + wn + ni * 16 + l16;
#pragma unroll
      for (int r = 0; r < 4; r++) {
        int row = m0 + wm + mi * 16 + q4 * 4 + r;
        float vv = acc[mi][ni][r];
        if (act) vv = (vv > 0.f) ? (vv + 1.f) : __expf(vv); // elu(x)+1
        Y[(size_t)row * 1024 + col] = f2bf(vv);
      }
    }
}

// ---------------- output GEMM: out = A * Wo^T + bo -> fp32 ----------------
__global__ __launch_bounds__(256) void out_kernel(
    const ushort_t* __restrict__ A, const ushort_t* __restrict__ Bw,
    float* __restrict__ Of, const float* __restrict__ bias) {
  __shared__ __align__(16) ushort_t Ash[128 * 32];
  __shared__ __align__(16) ushort_t Bsh[128 * 32];
  const int t = threadIdx.x;
  const int r_ = blockIdx.x, u_ = blockIdx.y;
  const int yb = r_ + 8 * (u_ & 7) + 64 * (u_ >> 6);
  const int xb = (u_ >> 3) & 7;
  const int m0 = yb * 128, n0 = xb * 128;
  const int w = t >> 6, lane = t & 63, q4 = lane >> 4, l16 = lane & 15;
  const int wm = (w >> 1) * 64, wn = (w & 1) * 64;

  f32x4 acc[4][4];
  const f32x4 zero = {0.f, 0.f, 0.f, 0.f};
#pragma unroll
  for (int i = 0; i < 4; i++)
#pragma unroll
    for (int j = 0; j < 4; j++) acc[i][j] = zero;

  for (int k0 = 0; k0 < 1024; k0 += 32) {
#pragma unroll
    for (int it = 0; it < 2; it++) {
      int lin = it * 256 + t;
      int row = lin >> 2, ch = (lin & 3) * 8;
      gld_lds16(A + (size_t)(m0 + row) * 1024 + k0 + ch, Ash + lin * 8);
      gld_lds16(Bw + (size_t)(n0 + row) * 1024 + k0 + ch, Bsh + lin * 8);
    }
    __syncthreads();
    bf16x8 af[4], bfm[4];
#pragma unroll
    for (int mi = 0; mi < 4; mi++) af[mi] = ldfrag(&Ash[(wm + mi * 16 + l16) * 32 + q4 * 8]);
#pragma unroll
    for (int ni = 0; ni < 4; ni++) bfm[ni] = ldfrag(&Bsh[(wn + ni * 16 + l16) * 32 + q4 * 8]);
#pragma unroll
    for (int mi = 0; mi < 4; mi++)
#pragma unroll
      for (int ni = 0; ni < 4; ni++)
        acc[mi][ni] = __builtin_amdgcn_mfma_f32_16x16x32_bf16(af[mi], bfm[ni], acc[mi][ni], 0, 0, 0);
    __syncthreads();
  }
#pragma unroll
  for (int mi = 0; mi < 4; mi++)
#pragma unroll
    for (int ni = 0; ni < 4; ni++) {
      int col = n0 + wn + ni * 16 + l16;
      float bv = bias[col];
#pragma unroll
      for (int r = 0; r < 4; r++) {
        int row = m0 + wm + mi * 16 + q4 * 4 + r;
        Of[(size_t)row * 1024 + col] = acc[mi][ni][r] + bv;
      }
    }
}

// ---------------- KV kernel: KVt[bh][e][d] = sum_s V[s,e]*K[s,d]; Ksum[bh][d]
// grid (4 s-chunks, 64 bh). MFMA with LDS-transposed reads (pad stride 66).
__global__ __launch_bounds__(256) void kv_kernel(
    const ushort_t* __restrict__ Kp, const ushort_t* __restrict__ Vp,
    float* __restrict__ KVt, float* __restrict__ Ksum) {
  const int bh = blockIdx.y, b = bh >> 4, h = bh & 15;
  const int schunk = blockIdx.x * 1024;
  const int t = threadIdx.x, w = t >> 6, lane = t & 63, q4 = lane >> 4, l16 = lane & 15;
  __shared__ ushort_t Ksh[64 * 66]; // row stride 66 ushorts = 33 dwords -> conflict-free transposed u16 reads
  __shared__ ushort_t Vsh[64 * 66];
  __shared__ float red[4][64];

  f32x4 acc[4];
  const f32x4 zero = {0.f, 0.f, 0.f, 0.f};
#pragma unroll
  for (int i = 0; i < 4; i++) acc[i] = zero;
  float ksum = 0.f;

  const int mat = t >> 7, tl = t & 127;
  const ushort_t* src = mat ? Vp : Kp;
  ushort_t* dsh = mat ? Vsh : Ksh;

  for (int tile = 0; tile < 16; tile++) {
    const int s0 = schunk + tile * 64;
    // stage 64x64 bf16 of K and V (threads 0..127 -> K, 128..255 -> V)
#pragma unroll
    for (int i = 0; i < 4; i++) {
      int idx = i * 1024 + tl * 8;
      int r = idx >> 6, c = idx & 63;
      const ushort_t* g = src + (size_t)(b * 4096 + s0 + r) * 1024 + h * 64 + c;
      uint4 u = *(const uint4*)g;
      unsigned int* p = (unsigned int*)&dsh[r * 66 + c];
      p[0] = u.x; p[1] = u.y; p[2] = u.z; p[3] = u.w;
    }
    __syncthreads();
    // wave w owns d-group [16w,16w+16); mi loops e-groups
#pragma unroll
    for (int ks = 0; ks < 2; ks++) {
      ushort_t tb[8];
#pragma unroll
      for (int j = 0; j < 8; j++) tb[j] = Ksh[(ks * 32 + q4 * 8 + j) * 66 + w * 16 + l16];
      bf16x8 bfr; __builtin_memcpy(&bfr, tb, 16);
#pragma unroll
      for (int mi = 0; mi < 4; mi++) {
        ushort_t ta[8];
#pragma unroll
        for (int j = 0; j < 8; j++) ta[j] = Vsh[(ks * 32 + q4 * 8 + j) * 66 + mi * 16 + l16];
        bf16x8 afr; __builtin_memcpy(&afr, ta, 16);
        acc[mi] = __builtin_amdgcn_mfma_f32_16x16x32_bf16(afr, bfr, acc[mi], 0, 0, 0);
      }
    }
    // Ksum partial: thread t sums rows [(t>>6)*16, +16) at col d = t&63
    {
      int d = t & 63;
#pragma unroll
      for (int r = 0; r < 16; r++) ksum += b2f(Ksh[((t >> 6) * 16 + r) * 66 + d]);
    }
    __syncthreads();
  }
  // C layout: row(m=e) = mi*16 + q4*4 + r ; col(n=d) = w*16 + l16
#pragma unroll
  for (int mi = 0; mi < 4; mi++)
#pragma unroll
    for (int r = 0; r < 4; r++) {
      int e = mi * 16 + q4 * 4 + r, d = w * 16 + l16;
      atomicAdd(&KVt[(size_t)bh * 4096 + e * 64 + d], acc[mi][r]);
    }
  red[t >> 6][t & 63] = ksum;
  __syncthreads();
  if (t < 64) atomicAdd(&Ksum[bh * 64 + t], red[0][t] + red[1][t] + red[2][t] + red[3][t]);
}

// ---------------- num kernel: Oc[s, h*64+e] = (Q_h KVt_h^T)/(Q_h.Ksum_h+1e-6)
// grid (16 s-tiles of 256, 64 bh)
__global__ __launch_bounds__(256) void num_kernel(
    const ushort_t* __restrict__ Qp, const float* __restrict__ KVt,
    const float* __restrict__ Ksum, ushort_t* __restrict__ Oc) {
  const int bh = blockIdx.y, b = bh >> 4, h = bh & 15;
  const int sblk = blockIdx.x * 256;
  const int t = threadIdx.x, w = t >> 6, lane = t & 63, q4 = lane >> 4, l16 = lane & 15;
  __shared__ __align__(16) ushort_t KVsh[64 * 72]; // stride 72 -> conflict-free b128 reads
  __shared__ float Ks_sh[64];
  __shared__ float rden[256];

#pragma unroll
  for (int i = 0; i < 16; i++) {
    int idx = i * 256 + t;
    int e = idx >> 6, d = idx & 63;
    KVsh[e * 72 + d] = f2bf(KVt[(size_t)bh * 4096 + idx]);
  }
  if (t < 64) Ks_sh[t] = Ksum[bh * 64 + t];
  __syncthreads();

  { // denominator for row sblk+t
    const ushort_t* qrow = Qp + (size_t)(b * 4096 + sblk + t) * 1024 + h * 64;
    float den = 1e-6f;
#pragma unroll
    for (int d = 0; d < 64; d++) den += b2f(qrow[d]) * Ks_sh[d];
    rden[t] = 1.f / den; // phi>0 -> den>0
  }
  __syncthreads();

  f32x4 acc[4][4];
  const f32x4 zero = {0.f, 0.f, 0.f, 0.f};
#pragma unroll
  for (int i = 0; i < 4; i++)
#pragma unroll
    for (int j = 0; j < 4; j++) acc[i][j] = zero;

#pragma unroll
  for (int ks = 0; ks < 2; ks++) {
    bf16x8 af[4], bfr[4];
#pragma unroll
    for (int mi = 0; mi < 4; mi++)
      af[mi] = ldfrag(Qp + (size_t)(b * 4096 + sblk + w * 64 + mi * 16 + l16) * 1024 + h * 64 + ks * 32 + q4 * 8);
#pragma unroll
    for (int ni = 0; ni < 4; ni++)
      bfr[ni] = ldfrag(&KVsh[(ni * 16 + l16) * 72 + ks * 32 + q4 * 8]);
#pragma unroll
    for (int mi = 0; mi < 4; mi++)
#pragma unroll
      for (int ni = 0; ni < 4; ni++)
        acc[mi][ni] = __builtin_amdgcn_mfma_f32_16x16x32_bf16(af[mi], bfr[ni], acc[mi][ni], 0, 0, 0);
  }
#pragma unroll
  for (int mi = 0; mi < 4; mi++)
#pragma unroll
    for (int ni = 0; ni < 4; ni++) {
      int e = ni * 16 + l16;
#pragma unroll
      for (int r = 0; r < 4; r++) {
        int srow = w * 64 + mi * 16 + q4 * 4 + r;
        float vv = acc[mi][ni][r] * rden[srow];
        Oc[(size_t)(b * 4096 + sblk + srow) * 1024 + h * 64 + e] = f2bf(vv);
      }
    }
}

extern "C" void kernel_launch(void* const* d_in, const int* in_sizes, int n_in,
                              void* d_out, int out_size, void* d_ws, size_t ws_size,
                              hipStream_t stream) {
  const float* q  = (const float*)d_in[0];
  const float* k  = (const float*)d_in[1];
  const float* v  = (const float*)d_in[2];
  const float* Wq = (const float*)d_in[3];
  const float* Wk = (const float*)d_in[4];
  const float* Wv = (const float*)d_in[5];
  const float* Wo = (const float*)d_in[6];
  const float* bo = (const float*)d_in[7];

  char* ws = (char*)d_ws;
  const size_t SZ_IN = (size_t)MM * DD * 2; // 33,554,432 B per bf16 [16384,1024]
  ushort_t* qbf = (ushort_t*)(ws);
  ushort_t* kbf = (ushort_t*)(ws + SZ_IN);
  ushort_t* vbf = (ushort_t*)(ws + 2 * SZ_IN);
  ushort_t* wqb = (ushort_t*)(ws + 3 * SZ_IN);
  ushort_t* wkb = wqb + (size_t)1024 * 1024;
  ushort_t* wvb = wkb + (size_t)1024 * 1024;
  ushort_t* wob = wvb + (size_t)1024 * 1024;
  ushort_t* Qp  = (ushort_t*)(ws + 3 * SZ_IN + 4 * (size_t)2097152);
  ushort_t* Kp  = Qp + (size_t)MM * DD;
  ushort_t* Vp  = Kp + (size_t)MM * DD;
  float* KVt    = (float*)((char*)(Vp + (size_t)MM * DD));
  float* KsumP  = KVt + (size_t)64 * 4096;
  ushort_t* Oc  = qbf; // reuse: qbf dead after proj dispatch
  float* outp   = (float*)d_out;

  hipMemsetAsync(KVt, 0, ((size_t)64 * 4096 + 64 * 64) * sizeof(float), stream);
  cast3_kernel<<<dim3(16384, 3), 256, 0, stream>>>(q, k, v, qbf, kbf, vbf);
  cast4_kernel<<<dim3(1024, 4), 256, 0, stream>>>(Wq, Wk, Wv, Wo, wqb, wkb, wvb, wob);
  proj_kernel<<<dim3(8, 128, 3), 256, 0, stream>>>(qbf, kbf, vbf, wqb, wkb, wvb, Qp, Kp, Vp);
  kv_kernel<<<dim3(4, 64), 256, 0, stream>>>(Kp, Vp, KVt, KsumP);
  num_kernel<<<dim3(16, 64), 256, 0, stream>>>(Qp, KVt, KsumP, Oc);
  out_kernel<<<dim3(8, 128), 256, 0, stream>>>(Oc, wob, outp, bo);
}

// Round 3
// 453.239 us; speedup vs baseline: 1.1216x; 1.0817x over previous
//
#include <hip/hip_runtime.h>

// LinearAttention: B=4, S=4096, D=1024, H=16, DK=64
// out = ((phi(xq Wq^T) @ (phi(xk Wk^T)^T @ (xv Wv^T)) / (phi(q).Ksum + 1e-6)) Wo^T + bo
// All GEMMs in bf16 MFMA (threshold = 2% of max|ref| -> bf16 is safe).
// R2: XCD swizzle (FETCH 399->98 MB, ideal) -- neutral on time => latency-bound.
// R3: double-buffered LDS K-loop in proj/out (stage k+1 before compute on k,
//     ONE barrier/iter -> load latency hidden under MFMA+ds_read phase);
//     kv grid 4->16 (1->4 blocks/CU); vectorized den dot in num.

typedef unsigned short ushort_t;
typedef __bf16 bf16x8 __attribute__((ext_vector_type(8)));
typedef float f32x4 __attribute__((ext_vector_type(4)));
typedef void gvoid_t __attribute__((address_space(1)));
typedef void svoid_t __attribute__((address_space(3)));

#define BB 4
#define SS 4096
#define DD 1024
#define HH 16
#define DKk 64
#define MM (BB * SS) /* 16384 */

__device__ __forceinline__ ushort_t f2bf(float f) {
  unsigned int u = __float_as_uint(f);
  u += 0x7fffu + ((u >> 16) & 1u); // RNE
  return (ushort_t)(u >> 16);
}
__device__ __forceinline__ float b2f(ushort_t h) {
  return __uint_as_float(((unsigned int)h) << 16);
}
__device__ __forceinline__ void gld_lds16(const ushort_t* g, ushort_t* l) {
  // async global->LDS, 16B per lane; LDS dest = wave-uniform base + lane*16
  __builtin_amdgcn_global_load_lds((gvoid_t*)g, (svoid_t*)l, 16, 0, 0);
}
__device__ __forceinline__ bf16x8 ldfrag(const ushort_t* p) {
  return *(const bf16x8*)p; // 16B aligned at all call sites
}

// ---------------- cast kernels (fp32 -> bf16) ----------------
__global__ __launch_bounds__(256) void cast3_kernel(
    const float* __restrict__ q, const float* __restrict__ k, const float* __restrict__ v,
    ushort_t* __restrict__ qd, ushort_t* __restrict__ kd, ushort_t* __restrict__ vd) {
  const int z = blockIdx.y;
  const float* s = (z == 0) ? q : (z == 1) ? k : v;
  ushort_t* d = (z == 0) ? qd : (z == 1) ? kd : vd;
  size_t i = ((size_t)blockIdx.x * 256 + threadIdx.x) * 4;
  float4 f = *(const float4*)(s + i);
  ushort4 o;
  o.x = f2bf(f.x); o.y = f2bf(f.y); o.z = f2bf(f.z); o.w = f2bf(f.w);
  *(ushort4*)(d + i) = o;
}

__global__ __launch_bounds__(256) void cast4_kernel(
    const float* __restrict__ a, const float* __restrict__ b,
    const float* __restrict__ c, const float* __restrict__ e,
    ushort_t* __restrict__ ad, ushort_t* __restrict__ bd,
    ushort_t* __restrict__ cd, ushort_t* __restrict__ ed) {
  const int z = blockIdx.y;
  const float* s = (z == 0) ? a : (z == 1) ? b : (z == 2) ? c : e;
  ushort_t* d = (z == 0) ? ad : (z == 1) ? bd : (z == 2) ? cd : ed;
  size_t i = ((size_t)blockIdx.x * 256 + threadIdx.x) * 4;
  float4 f = *(const float4*)(s + i);
  ushort4 o;
  o.x = f2bf(f.x); o.y = f2bf(f.y); o.z = f2bf(f.z); o.w = f2bf(f.w);
  *(ushort4*)(d + i) = o;
}

// ---------------- projection GEMM: Y = act(A[M,K] * W[N,K]^T) -> bf16 ------
// 128x128 tile, BK=32, 4 waves, 4x4 16x16x32 frags; DOUBLE-BUFFERED LDS.
__global__ __launch_bounds__(256) void proj_kernel(
    const ushort_t* __restrict__ qa, const ushort_t* __restrict__ ka, const ushort_t* __restrict__ va,
    const ushort_t* __restrict__ wq, const ushort_t* __restrict__ wk, const ushort_t* __restrict__ wv,
    ushort_t* __restrict__ Qp, ushort_t* __restrict__ Kp, ushort_t* __restrict__ Vp) {
  const int z = blockIdx.z;
  const ushort_t* A = (z == 0) ? qa : (z == 1) ? ka : va;
  const ushort_t* Bw = (z == 0) ? wq : (z == 1) ? wk : wv;
  ushort_t* Y = (z == 0) ? Qp : (z == 1) ? Kp : Vp;
  const bool act = (z < 2); // phi = elu+1 on Q,K only

  __shared__ __align__(16) ushort_t Ash[2][128 * 32];
  __shared__ __align__(16) ushort_t Bsh[2][128 * 32];
  const int t = threadIdx.x;
  // XCD swizzle: r = blockIdx.x is the XCD (gridDim.x=8, round-robin).
  const int r_ = blockIdx.x, u_ = blockIdx.y;
  const int yb = r_ + 8 * (u_ & 7) + 64 * (u_ >> 6);
  const int xb = (u_ >> 3) & 7;
  const int m0 = yb * 128, n0 = xb * 128;
  const int w = t >> 6, lane = t & 63, q4 = lane >> 4, l16 = lane & 15;
  const int wm = (w >> 1) * 64, wn = (w & 1) * 64;
  const int srow = t >> 2, sch = (t & 3) * 8; // staging row/col for this thread

  f32x4 acc[4][4];
  const f32x4 zero = {0.f, 0.f, 0.f, 0.f};
#pragma unroll
  for (int i = 0; i < 4; i++)
#pragma unroll
    for (int j = 0; j < 4; j++) acc[i][j] = zero;

  const ushort_t* ga = A + (size_t)(m0 + srow) * 1024 + sch;
  const ushort_t* gb = Bw + (size_t)(n0 + srow) * 1024 + sch;

  // prologue: stage k0=0 into buf 0
  gld_lds16(ga + 0, &Ash[0][t * 8]);
  gld_lds16(ga + 64 * 1024, &Ash[0][(256 + t) * 8]);
  gld_lds16(gb + 0, &Bsh[0][t * 8]);
  gld_lds16(gb + 64 * 1024, &Bsh[0][(256 + t) * 8]);
  __syncthreads();

  int cur = 0;
  for (int k0 = 0; k0 < 1024; k0 += 32, cur ^= 1) {
    if (k0 + 32 < 1024) { // stage next tile into buf cur^1 (overlaps compute)
      gld_lds16(ga + (k0 + 32), &Ash[cur ^ 1][t * 8]);
      gld_lds16(ga + (k0 + 32) + 64 * 1024, &Ash[cur ^ 1][(256 + t) * 8]);
      gld_lds16(gb + (k0 + 32), &Bsh[cur ^ 1][t * 8]);
      gld_lds16(gb + (k0 + 32) + 64 * 1024, &Bsh[cur ^ 1][(256 + t) * 8]);
    }
    bf16x8 af[4], bfm[4];
#pragma unroll
    for (int mi = 0; mi < 4; mi++) af[mi] = ldfrag(&Ash[cur][(wm + mi * 16 + l16) * 32 + q4 * 8]);
#pragma unroll
    for (int ni = 0; ni < 4; ni++) bfm[ni] = ldfrag(&Bsh[cur][(wn + ni * 16 + l16) * 32 + q4 * 8]);
#pragma unroll
    for (int mi = 0; mi < 4; mi++)
#pragma unroll
      for (int ni = 0; ni < 4; ni++)
        acc[mi][ni] = __builtin_amdgcn_mfma_f32_16x16x32_bf16(af[mi], bfm[ni], acc[mi][ni], 0, 0, 0);
    __syncthreads(); // one barrier/iter: drains next-stage vmcnt (mostly done) + guards buf reuse
  }
#pragma unroll
  for (int mi = 0; mi < 4; mi++)
#pragma unroll
    for (int ni = 0; ni < 4; ni++) {
      int col = n0 + wn + ni * 16 + l16;
#pragma unroll
      for (int r = 0; r < 4; r++) {
        int row = m0 + wm + mi * 16 + q4 * 4 + r;
        float vv = acc[mi][ni][r];
        if (act) vv = (vv > 0.f) ? (vv + 1.f) : __expf(vv); // elu(x)+1
        Y[(size_t)row * 1024 + col] = f2bf(vv);
      }
    }
}

// ---------------- output GEMM: out = A * Wo^T + bo -> fp32 ----------------
__global__ __launch_bounds__(256) void out_kernel(
    const ushort_t* __restrict__ A, const ushort_t* __restrict__ Bw,
    float* __restrict__ Of, const float* __restrict__ bias) {
  __shared__ __align__(16) ushort_t Ash[2][128 * 32];
  __shared__ __align__(16) ushort_t Bsh[2][128 * 32];
  const int t = threadIdx.x;
  const int r_ = blockIdx.x, u_ = blockIdx.y;
  const int yb = r_ + 8 * (u_ & 7) + 64 * (u_ >> 6);
  const int xb = (u_ >> 3) & 7;
  const int m0 = yb * 128, n0 = xb * 128;
  const int w = t >> 6, lane = t & 63, q4 = lane >> 4, l16 = lane & 15;
  const int wm = (w >> 1) * 64, wn = (w & 1) * 64;
  const int srow = t >> 2, sch = (t & 3) * 8;

  f32x4 acc[4][4];
  const f32x4 zero = {0.f, 0.f, 0.f, 0.f};
#pragma unroll
  for (int i = 0; i < 4; i++)
#pragma unroll
    for (int j = 0; j < 4; j++) acc[i][j] = zero;

  const ushort_t* ga = A + (size_t)(m0 + srow) * 1024 + sch;
  const ushort_t* gb = Bw + (size_t)(n0 + srow) * 1024 + sch;

  gld_lds16(ga + 0, &Ash[0][t * 8]);
  gld_lds16(ga + 64 * 1024, &Ash[0][(256 + t) * 8]);
  gld_lds16(gb + 0, &Bsh[0][t * 8]);
  gld_lds16(gb + 64 * 1024, &Bsh[0][(256 + t) * 8]);
  __syncthreads();

  int cur = 0;
  for (int k0 = 0; k0 < 1024; k0 += 32, cur ^= 1) {
    if (k0 + 32 < 1024) {
      gld_lds16(ga + (k0 + 32), &Ash[cur ^ 1][t * 8]);
      gld_lds16(ga + (k0 + 32) + 64 * 1024, &Ash[cur ^ 1][(256 + t) * 8]);
      gld_lds16(gb + (k0 + 32), &Bsh[cur ^ 1][t * 8]);
      gld_lds16(gb + (k0 + 32) + 64 * 1024, &Bsh[cur ^ 1][(256 + t) * 8]);
    }
    bf16x8 af[4], bfm[4];
#pragma unroll
    for (int mi = 0; mi < 4; mi++) af[mi] = ldfrag(&Ash[cur][(wm + mi * 16 + l16) * 32 + q4 * 8]);
#pragma unroll
    for (int ni = 0; ni < 4; ni++) bfm[ni] = ldfrag(&Bsh[cur][(wn + ni * 16 + l16) * 32 + q4 * 8]);
#pragma unroll
    for (int mi = 0; mi < 4; mi++)
#pragma unroll
      for (int ni = 0; ni < 4; ni++)
        acc[mi][ni] = __builtin_amdgcn_mfma_f32_16x16x32_bf16(af[mi], bfm[ni], acc[mi][ni], 0, 0, 0);
    __syncthreads();
  }
#pragma unroll
  for (int mi = 0; mi < 4; mi++)
#pragma unroll
    for (int ni = 0; ni < 4; ni++) {
      int col = n0 + wn + ni * 16 + l16;
      float bv = bias[col];
#pragma unroll
      for (int r = 0; r < 4; r++) {
        int row = m0 + wm + mi * 16 + q4 * 4 + r;
        Of[(size_t)row * 1024 + col] = acc[mi][ni][r] + bv;
      }
    }
}

// ---------------- KV kernel: KVt[bh][e][d] = sum_s V[s,e]*K[s,d]; Ksum[bh][d]
// grid (16 s-chunks, 64 bh) = 1024 blocks (4 blocks/CU for latency hiding).
__global__ __launch_bounds__(256) void kv_kernel(
    const ushort_t* __restrict__ Kp, const ushort_t* __restrict__ Vp,
    float* __restrict__ KVt, float* __restrict__ Ksum) {
  const int bh = blockIdx.y, b = bh >> 4, h = bh & 15;
  const int schunk = blockIdx.x * 256;
  const int t = threadIdx.x, w = t >> 6, lane = t & 63, q4 = lane >> 4, l16 = lane & 15;
  __shared__ ushort_t Ksh[64 * 66]; // row stride 66 ushorts = 33 dwords -> conflict-free transposed u16 reads
  __shared__ ushort_t Vsh[64 * 66];
  __shared__ float red[4][64];

  f32x4 acc[4];
  const f32x4 zero = {0.f, 0.f, 0.f, 0.f};
#pragma unroll
  for (int i = 0; i < 4; i++) acc[i] = zero;
  float ksum = 0.f;

  const int mat = t >> 7, tl = t & 127;
  const ushort_t* src = mat ? Vp : Kp;
  ushort_t* dsh = mat ? Vsh : Ksh;

  for (int tile = 0; tile < 4; tile++) {
    const int s0 = schunk + tile * 64;
    // stage 64x64 bf16 of K and V (threads 0..127 -> K, 128..255 -> V)
#pragma unroll
    for (int i = 0; i < 4; i++) {
      int idx = i * 1024 + tl * 8;
      int r = idx >> 6, c = idx & 63;
      const ushort_t* g = src + (size_t)(b * 4096 + s0 + r) * 1024 + h * 64 + c;
      uint4 u = *(const uint4*)g;
      unsigned int* p = (unsigned int*)&dsh[r * 66 + c];
      p[0] = u.x; p[1] = u.y; p[2] = u.z; p[3] = u.w;
    }
    __syncthreads();
    // wave w owns d-group [16w,16w+16); mi loops e-groups
#pragma unroll
    for (int ks = 0; ks < 2; ks++) {
      ushort_t tb[8];
#pragma unroll
      for (int j = 0; j < 8; j++) tb[j] = Ksh[(ks * 32 + q4 * 8 + j) * 66 + w * 16 + l16];
      bf16x8 bfr; __builtin_memcpy(&bfr, tb, 16);
#pragma unroll
      for (int mi = 0; mi < 4; mi++) {
        ushort_t ta[8];
#pragma unroll
        for (int j = 0; j < 8; j++) ta[j] = Vsh[(ks * 32 + q4 * 8 + j) * 66 + mi * 16 + l16];
        bf16x8 afr; __builtin_memcpy(&afr, ta, 16);
        acc[mi] = __builtin_amdgcn_mfma_f32_16x16x32_bf16(afr, bfr, acc[mi], 0, 0, 0);
      }
    }
    // Ksum partial: thread t sums rows [(t>>6)*16, +16) at col d = t&63
    {
      int d = t & 63;
#pragma unroll
      for (int r = 0; r < 16; r++) ksum += b2f(Ksh[((t >> 6) * 16 + r) * 66 + d]);
    }
    __syncthreads();
  }
  // C layout: row(m=e) = mi*16 + q4*4 + r ; col(n=d) = w*16 + l16
#pragma unroll
  for (int mi = 0; mi < 4; mi++)
#pragma unroll
    for (int r = 0; r < 4; r++) {
      int e = mi * 16 + q4 * 4 + r, d = w * 16 + l16;
      atomicAdd(&KVt[(size_t)bh * 4096 + e * 64 + d], acc[mi][r]);
    }
  red[t >> 6][t & 63] = ksum;
  __syncthreads();
  if (t < 64) atomicAdd(&Ksum[bh * 64 + t], red[0][t] + red[1][t] + red[2][t] + red[3][t]);
}

// ---------------- num kernel: Oc[s, h*64+e] = (Q_h KVt_h^T)/(Q_h.Ksum_h+1e-6)
// grid (16 s-tiles of 256, 64 bh)
__global__ __launch_bounds__(256) void num_kernel(
    const ushort_t* __restrict__ Qp, const float* __restrict__ KVt,
    const float* __restrict__ Ksum, ushort_t* __restrict__ Oc) {
  const int bh = blockIdx.y, b = bh >> 4, h = bh & 15;
  const int sblk = blockIdx.x * 256;
  const int t = threadIdx.x, w = t >> 6, lane = t & 63, q4 = lane >> 4, l16 = lane & 15;
  __shared__ __align__(16) ushort_t KVsh[64 * 72]; // stride 72 -> conflict-free b128 reads
  __shared__ float Ks_sh[64];
  __shared__ float rden[256];

#pragma unroll
  for (int i = 0; i < 16; i++) {
    int idx = i * 256 + t;
    int e = idx >> 6, d = idx & 63;
    KVsh[e * 72 + d] = f2bf(KVt[(size_t)bh * 4096 + idx]);
  }
  if (t < 64) Ks_sh[t] = Ksum[bh * 64 + t];
  __syncthreads();

  { // denominator for row sblk+t (vectorized bf16x8 loads)
    const ushort_t* qrow = Qp + (size_t)(b * 4096 + sblk + t) * 1024 + h * 64;
    float den = 1e-6f;
#pragma unroll
    for (int j = 0; j < 8; j++) {
      bf16x8 qv = ldfrag(qrow + j * 8);
#pragma unroll
      for (int e = 0; e < 8; e++) den += (float)qv[e] * Ks_sh[j * 8 + e];
    }
    rden[t] = 1.f / den; // phi>0 -> den>0
  }
  __syncthreads();

  f32x4 acc[4][4];
  const f32x4 zero = {0.f, 0.f, 0.f, 0.f};
#pragma unroll
  for (int i = 0; i < 4; i++)
#pragma unroll
    for (int j = 0; j < 4; j++) acc[i][j] = zero;

#pragma unroll
  for (int ks = 0; ks < 2; ks++) {
    bf16x8 af[4], bfr[4];
#pragma unroll
    for (int mi = 0; mi < 4; mi++)
      af[mi] = ldfrag(Qp + (size_t)(b * 4096 + sblk + w * 64 + mi * 16 + l16) * 1024 + h * 64 + ks * 32 + q4 * 8);
#pragma unroll
    for (int ni = 0; ni < 4; ni++)
      bfr[ni] = ldfrag(&KVsh[(ni * 16 + l16) * 72 + ks * 32 + q4 * 8]);
#pragma unroll
    for (int mi = 0; mi < 4; mi++)
#pragma unroll
      for (int ni = 0; ni < 4; ni++)
        acc[mi][ni] = __builtin_amdgcn_mfma_f32_16x16x32_bf16(af[mi], bfr[ni], acc[mi][ni], 0, 0, 0);
  }
#pragma unroll
  for (int mi = 0; mi < 4; mi++)
#pragma unroll
    for (int ni = 0; ni < 4; ni++) {
      int e = ni * 16 + l16;
#pragma unroll
      for (int r = 0; r < 4; r++) {
        int srow = w * 64 + mi * 16 + q4 * 4 + r;
        float vv = acc[mi][ni][r] * rden[srow];
        Oc[(size_t)(b * 4096 + sblk + srow) * 1024 + h * 64 + e] = f2bf(vv);
      }
    }
}

extern "C" void kernel_launch(void* const* d_in, const int* in_sizes, int n_in,
                              void* d_out, int out_size, void* d_ws, size_t ws_size,
                              hipStream_t stream) {
  const float* q  = (const float*)d_in[0];
  const float* k  = (const float*)d_in[1];
  const float* v  = (const float*)d_in[2];
  const float* Wq = (const float*)d_in[3];
  const float* Wk = (const float*)d_in[4];
  const float* Wv = (const float*)d_in[5];
  const float* Wo = (const float*)d_in[6];
  const float* bo = (const float*)d_in[7];

  char* ws = (char*)d_ws;
  const size_t SZ_IN = (size_t)MM * DD * 2; // 33,554,432 B per bf16 [16384,1024]
  ushort_t* qbf = (ushort_t*)(ws);
  ushort_t* kbf = (ushort_t*)(ws + SZ_IN);
  ushort_t* vbf = (ushort_t*)(ws + 2 * SZ_IN);
  ushort_t* wqb = (ushort_t*)(ws + 3 * SZ_IN);
  ushort_t* wkb = wqb + (size_t)1024 * 1024;
  ushort_t* wvb = wkb + (size_t)1024 * 1024;
  ushort_t* wob = wvb + (size_t)1024 * 1024;
  ushort_t* Qp  = (ushort_t*)(ws + 3 * SZ_IN + 4 * (size_t)2097152);
  ushort_t* Kp  = Qp + (size_t)MM * DD;
  ushort_t* Vp  = Kp + (size_t)MM * DD;
  float* KVt    = (float*)((char*)(Vp + (size_t)MM * DD));
  float* KsumP  = KVt + (size_t)64 * 4096;
  ushort_t* Oc  = qbf; // reuse: qbf dead after proj dispatch
  float* outp   = (float*)d_out;

  hipMemsetAsync(KVt, 0, ((size_t)64 * 4096 + 64 * 64) * sizeof(float), stream);
  cast3_kernel<<<dim3(16384, 3), 256, 0, stream>>>(q, k, v, qbf, kbf, vbf);
  cast4_kernel<<<dim3(1024, 4), 256, 0, stream>>>(Wq, Wk, Wv, Wo, wqb, wkb, wvb, wob);
  proj_kernel<<<dim3(8, 128, 3), 256, 0, stream>>>(qbf, kbf, vbf, wqb, wkb, wvb, Qp, Kp, Vp);
  kv_kernel<<<dim3(16, 64), 256, 0, stream>>>(Kp, Vp, KVt, KsumP);
  num_kernel<<<dim3(16, 64), 256, 0, stream>>>(Qp, KVt, KsumP, Oc);
  out_kernel<<<dim3(8, 128), 256, 0, stream>>>(Oc, wob, outp, bo);
}